// Round 1
// baseline (253.191 us; speedup 1.0000x reference)
//
#include <hip/hip_runtime.h>
#include <math.h>

#define NPTS 200001
#define TRAPZ_BLOCKS 200

// ---------------------------------------------------------------------------
// prep_a: blocks [0,200): fp64 trapz partial sums for SILU_C / SIG_C
//         blocks [200,221): build combined+scaled weights into workspace
// ---------------------------------------------------------------------------
__global__ void prep_a(const float* __restrict__ wss0, const float* __restrict__ wvv0,
                       const float* __restrict__ wss1, const float* __restrict__ wvv1,
                       const float* __restrict__ wsv,  const float* __restrict__ wvs,
                       double* __restrict__ partials,
                       float* __restrict__ wssc, float* __restrict__ wvvc,
                       float* __restrict__ wgc)
{
    const int b = blockIdx.x;
    const int t = threadIdx.x;
    if (b < TRAPZ_BLOCKS) {
        const int gid = b * 256 + t;
        double ls = 0.0, lg = 0.0;
        for (int i = gid; i < NPTS; i += TRAPZ_BLOCKS * 256) {
            double xv  = -12.0 + 24.0 * ((double)i / 200000.0);
            double pdf = exp(-0.5 * xv * xv) / sqrt(2.0 * 3.14159265358979323846);
            double sg  = 1.0 / (1.0 + exp(-xv));
            double si  = xv * sg;
            double wt  = (i == 0 || i == NPTS - 1) ? 0.5 : 1.0;
            ls += wt * si * si * pdf;
            lg += wt * sg * sg * pdf;
        }
        __shared__ double r1[256], r2[256];
        r1[t] = ls; r2[t] = lg;
        __syncthreads();
        for (int st = 128; st > 0; st >>= 1) {
            if (t < st) { r1[t] += r1[t + st]; r2[t] += r2[t + st]; }
            __syncthreads();
        }
        if (t == 0) { partials[b] = r1[0]; partials[TRAPZ_BLOCKS + b] = r2[0]; }
    } else {
        const int gid = (b - TRAPZ_BLOCKS) * 256 + t;
        // C_SC = 1/sqrt(MUL_S^2 + MUL_V^2) = 1/sqrt(320); vv term gets extra /sqrt(3)
        const float CSC  = (float)(0.05590169943749474241);
        const float CSC3 = (float)(0.05590169943749474241 / 1.7320508075688772935);
        if (gid < 3264) {                       // wssc[pair(136)][24]
            int p = gid / 24, w = gid % 24;
            int u = 0, rem = p;
            while (rem >= 16 - u) { rem -= 16 - u; ++u; }
            int tt = u + rem;                   // u <= tt
            float val;
            if (w < 16) {
                val = wss0[(u * 16 + tt) * 16 + w];
                if (tt != u) val += wss0[(tt * 16 + u) * 16 + w];
            } else {
                val = wss1[(u * 16 + tt) * 8 + (w - 16)];
                if (tt != u) val += wss1[(tt * 16 + u) * 8 + (w - 16)];
            }
            wssc[gid] = CSC * val;
        } else if (gid < 4128) {                // wvvc[pair(36)][24]
            int q = gid - 3264;
            int p = q / 24, w = q % 24;
            int u = 0, rem = p;
            while (rem >= 8 - u) { rem -= 8 - u; ++u; }
            int tt = u + rem;
            float val;
            if (w < 16) {
                val = wvv0[(u * 8 + tt) * 16 + w];
                if (tt != u) val += wvv0[(tt * 8 + u) * 16 + w];
            } else {
                val = wvv1[(u * 8 + tt) * 8 + (w - 16)];
                if (tt != u) val += wvv1[(tt * 8 + u) * 8 + (w - 16)];
            }
            wvvc[q] = CSC3 * val;
        } else if (gid < 5152) {                // wgc[b(8)][w(8)][a(16)]
            int q = gid - 4128;
            int bb = q >> 7;
            int w  = (q >> 4) & 7;
            int a  = q & 15;
            // C_V/SQRT3 = sqrt(3/256)/sqrt(3) = 1/16 exactly
            wgc[q] = 0.0625f * (wsv[(a * 8 + bb) * 8 + w] + wvs[(bb * 16 + a) * 8 + w]);
        }
    }
}

// ---------------------------------------------------------------------------
// prep_b: reduce trapz partials -> SILU_C, SIG_C (fp64, matches np.trapz)
// ---------------------------------------------------------------------------
__global__ void prep_b(const double* __restrict__ partials, float* __restrict__ cons)
{
    const int t = threadIdx.x;
    __shared__ double r1[256], r2[256];
    r1[t] = (t < TRAPZ_BLOCKS) ? partials[t] : 0.0;
    r2[t] = (t < TRAPZ_BLOCKS) ? partials[TRAPZ_BLOCKS + t] : 0.0;
    __syncthreads();
    for (int st = 128; st > 0; st >>= 1) {
        if (t < st) { r1[t] += r1[t + st]; r2[t] += r2[t + st]; }
        __syncthreads();
    }
    if (t == 0) {
        double dx = 24.0 / 200000.0;
        cons[0] = (float)(1.0 / sqrt(r1[0] * dx));   // SILU_C
        cons[1] = (float)(1.0 / sqrt(r2[0] * dx));   // SIG_C
    }
}

// ---------------------------------------------------------------------------
// Main kernel: one thread per row. Row staged in transposed LDS so rolled
// (uniform) pair-loop indices can address it; accumulators in registers;
// weights stream through the scalar path (uniform indices, __restrict__).
// ---------------------------------------------------------------------------
__global__ __launch_bounds__(256) void seg_main(
    const float* __restrict__ x,
    const float* __restrict__ wssc,   // [136][24]
    const float* __restrict__ wvvc,   // [36][24]
    const float* __restrict__ wgc,    // [8][8][16]
    const float* __restrict__ cons,   // [2]
    float* __restrict__ out, int n)
{
    __shared__ float xs[40][256];     // 40960 B -> exactly 4 blocks/CU
    const int tid = threadIdx.x;
    const int row = blockIdx.x * 256 + tid;
    const int lrow = (row < n) ? row : (n - 1);

    float xr[40] __attribute__((aligned(16)));
    const float4* xp = (const float4*)(x + (size_t)lrow * 40);
#pragma unroll
    for (int k = 0; k < 10; ++k) ((float4*)xr)[k] = xp[k];
#pragma unroll
    for (int c = 0; c < 40; ++c) xs[c][tid] = xr[c];
    // no __syncthreads needed: each thread reads only its own column

    float acc[24];
#pragma unroll
    for (int w = 0; w < 24; ++w) acc[w] = 0.f;

    // ---- s (x) s quadratic features: 136 symmetrized pairs ----
    const float* wp = wssc;
#pragma unroll 1
    for (int u = 0; u < 16; ++u) {
        float su = xs[u][tid];
#pragma unroll 1
        for (int t2 = u; t2 < 16; ++t2) {
            float pr = su * xs[t2][tid];
#pragma unroll
            for (int w = 0; w < 24; ++w) acc[w] = fmaf(pr, wp[w], acc[w]);
            wp += 24;
        }
    }

    // ---- <v_u, v_t> features: 36 symmetrized pairs ----
    wp = wvvc;
#pragma unroll 1
    for (int u = 0; u < 8; ++u) {
        float a0 = xs[16 + 3 * u + 0][tid];
        float a1 = xs[16 + 3 * u + 1][tid];
        float a2 = xs[16 + 3 * u + 2][tid];
#pragma unroll 1
        for (int t2 = u; t2 < 8; ++t2) {
            float d = a0 * xs[16 + 3 * t2 + 0][tid];
            d = fmaf(a1, xs[16 + 3 * t2 + 1][tid], d);
            d = fmaf(a2, xs[16 + 3 * t2 + 2][tid], d);
#pragma unroll
            for (int w = 0; w < 24; ++w) acc[w] = fmaf(d, wp[w], acc[w]);
            wp += 24;
        }
    }

    // ---- gated[w][i] = sum_b v[b][i] * (sum_a s[a]*Wg[b][w][a]) ----
    float gated[24];
#pragma unroll
    for (int k = 0; k < 24; ++k) gated[k] = 0.f;
#pragma unroll 1
    for (int b = 0; b < 8; ++b) {
        float vb0 = xs[16 + 3 * b + 0][tid];
        float vb1 = xs[16 + 3 * b + 1][tid];
        float vb2 = xs[16 + 3 * b + 2][tid];
        const float* wq = wgc + b * 128;
#pragma unroll
        for (int w = 0; w < 8; ++w) {
            float tacc = 0.f;
#pragma unroll
            for (int a = 0; a < 16; ++a) tacc = fmaf(xr[a], wq[w * 16 + a], tacc);
            gated[3 * w + 0] = fmaf(tacc, vb0, gated[3 * w + 0]);
            gated[3 * w + 1] = fmaf(tacc, vb1, gated[3 * w + 1]);
            gated[3 * w + 2] = fmaf(tacc, vb2, gated[3 * w + 2]);
        }
    }

    // ---- activations + output ----
    const float silu_c = cons[0];
    const float sig_c  = cons[1];
    float o[40] __attribute__((aligned(16)));
#pragma unroll
    for (int w = 0; w < 16; ++w) {
        float z = acc[w];
        float e = __expf(-z);
        o[w] = silu_c * z / (1.f + e);
    }
#pragma unroll
    for (int w = 0; w < 8; ++w) {
        float z = acc[16 + w];
        float e = __expf(-z);
        float g = sig_c / (1.f + e);
        o[16 + 3 * w + 0] = g * gated[3 * w + 0];
        o[16 + 3 * w + 1] = g * gated[3 * w + 1];
        o[16 + 3 * w + 2] = g * gated[3 * w + 2];
    }
    if (row < n) {
        float4* op = (float4*)(out + (size_t)row * 40);
#pragma unroll
        for (int k = 0; k < 10; ++k) op[k] = ((const float4*)o)[k];
    }
}

// ---------------------------------------------------------------------------
extern "C" void kernel_launch(void* const* d_in, const int* in_sizes, int n_in,
                              void* d_out, int out_size, void* d_ws, size_t ws_size,
                              hipStream_t stream)
{
    (void)n_in; (void)out_size; (void)ws_size;
    const float* x    = (const float*)d_in[0];
    const float* wss0 = (const float*)d_in[1];
    const float* wvv0 = (const float*)d_in[2];
    const float* wss1 = (const float*)d_in[3];
    const float* wvv1 = (const float*)d_in[4];
    const float* wsv  = (const float*)d_in[5];
    const float* wvs  = (const float*)d_in[6];
    float* out = (float*)d_out;
    const int n = in_sizes[0] / 40;

    char* ws = (char*)d_ws;
    float*  cons     = (float*)(ws + 0);        // 2 floats
    double* partials = (double*)(ws + 64);      // 400 doubles -> ends 3264
    float*  wssc     = (float*)(ws + 4096);     // 3264 floats -> ends 17152
    float*  wvvc     = (float*)(ws + 17408);    // 864 floats  -> ends 20864
    float*  wgc      = (float*)(ws + 21504);    // 1024 floats -> ends 25600

    hipLaunchKernelGGL(prep_a, dim3(TRAPZ_BLOCKS + 21), dim3(256), 0, stream,
                       wss0, wvv0, wss1, wvv1, wsv, wvs, partials, wssc, wvvc, wgc);
    hipLaunchKernelGGL(prep_b, dim3(1), dim3(256), 0, stream, partials, cons);
    hipLaunchKernelGGL(seg_main, dim3((n + 255) / 256), dim3(256), 0, stream,
                       x, wssc, wvvc, wgc, cons, out, n);
}

// Round 2
// 228.960 us; speedup vs baseline: 1.1058x; 1.1058x over previous
//
#include <hip/hip_runtime.h>
#include <hip/hip_fp16.h>
#include <math.h>

#define NPTS 200001

// ---------------------------------------------------------------------------
// prep: blocks 0..3   : fp32 trapz partial sums for SILU_C / SIG_C
//       blocks 4..24  : build combined+scaled weights into workspace
// ---------------------------------------------------------------------------
__global__ void prep(const float* __restrict__ wss0, const float* __restrict__ wvv0,
                     const float* __restrict__ wss1, const float* __restrict__ wvv1,
                     const float* __restrict__ wsv,  const float* __restrict__ wvs,
                     float* __restrict__ partials,
                     float* __restrict__ wssc, float* __restrict__ wvvc,
                     float* __restrict__ wgc)
{
    const int b = blockIdx.x;
    const int t = threadIdx.x;
    if (b < 4) {
        float ls = 0.f, lg = 0.f;
        for (int i = b * 256 + t; i < NPTS; i += 1024) {
            float xv  = -12.0f + 24.0f * ((float)i / 200000.0f);
            float pdf = __expf(-0.5f * xv * xv) * 0.39894228040143267794f;
            float sg  = 1.0f / (1.0f + __expf(-xv));
            float si  = xv * sg;
            float wt  = (i == 0 || i == NPTS - 1) ? 0.5f : 1.0f;
            ls = fmaf(wt * si * si, pdf, ls);
            lg = fmaf(wt * sg * sg, pdf, lg);
        }
        __shared__ float r1[256], r2[256];
        r1[t] = ls; r2[t] = lg;
        __syncthreads();
        for (int st = 128; st > 0; st >>= 1) {
            if (t < st) { r1[t] += r1[t + st]; r2[t] += r2[t + st]; }
            __syncthreads();
        }
        if (t == 0) { partials[b] = r1[0]; partials[4 + b] = r2[0]; }
    } else {
        const int gid = (b - 4) * 256 + t;
        const float CSC  = (float)(0.05590169943749474241);                      // 1/sqrt(320)
        const float CSC3 = (float)(0.05590169943749474241 / 1.7320508075688772935);
        if (gid < 3264) {                       // wssc[pair(136)][24]
            int p = gid / 24, w = gid % 24;
            int u = 0, rem = p;
            while (rem >= 16 - u) { rem -= 16 - u; ++u; }
            int tt = u + rem;                   // u <= tt
            float val;
            if (w < 16) {
                val = wss0[(u * 16 + tt) * 16 + w];
                if (tt != u) val += wss0[(tt * 16 + u) * 16 + w];
            } else {
                val = wss1[(u * 16 + tt) * 8 + (w - 16)];
                if (tt != u) val += wss1[(tt * 16 + u) * 8 + (w - 16)];
            }
            wssc[gid] = CSC * val;
        } else if (gid < 4128) {                // wvvc[pair(36)][24]
            int q = gid - 3264;
            int p = q / 24, w = q % 24;
            int u = 0, rem = p;
            while (rem >= 8 - u) { rem -= 8 - u; ++u; }
            int tt = u + rem;
            float val;
            if (w < 16) {
                val = wvv0[(u * 8 + tt) * 16 + w];
                if (tt != u) val += wvv0[(tt * 8 + u) * 16 + w];
            } else {
                val = wvv1[(u * 8 + tt) * 8 + (w - 16)];
                if (tt != u) val += wvv1[(tt * 8 + u) * 8 + (w - 16)];
            }
            wvvc[q] = CSC3 * val;
        } else if (gid < 5152) {                // wgc[b(8)][a(16)][w(8)]  (a-major!)
            int q  = gid - 4128;
            int bb = q >> 7;
            int a  = (q >> 3) & 15;
            int w  = q & 7;
            // C_V/SQRT3 = 1/16 exactly
            wgc[q] = 0.0625f * (wsv[(a * 8 + bb) * 8 + w] + wvs[(bb * 16 + a) * 8 + w]);
        }
    }
}

// ---------------------------------------------------------------------------
// Main kernel: 2 rows per thread, packed as half2 (row-pair) per component in
// LDS. Every ds_read_b32 feeds 48 FMAs (24 outputs x 2 rows); weights stream
// through the scalar path with a 96-FMA unrolled window for prefetch.
// ---------------------------------------------------------------------------
__global__ __launch_bounds__(256) void seg_main(
    const float* __restrict__ x,
    const float* __restrict__ wssc,   // [136][24]
    const float* __restrict__ wvvc,   // [36][24]
    const float* __restrict__ wgc,    // [8][16][8]
    const float* __restrict__ partials, // [8]
    float* __restrict__ out, int n)
{
    __shared__ __half2 xs[40][256];   // 40 KB -> 4 blocks/CU, 16 waves
    const int tid = threadIdx.x;
    const int r0 = blockIdx.x * 512 + 2 * tid;
    const int r1 = r0 + 1;
    const int l0 = (r0 < n) ? r0 : n - 1;
    const int l1 = (r1 < n) ? r1 : n - 1;

    // ---- stage both rows into LDS as packed half2 ----
    {
        float A[40] __attribute__((aligned(16)));
        float B[40] __attribute__((aligned(16)));
        const float4* p0 = (const float4*)(x + (size_t)l0 * 40);
        const float4* p1 = (const float4*)(x + (size_t)l1 * 40);
#pragma unroll
        for (int k = 0; k < 10; ++k) { ((float4*)A)[k] = p0[k]; ((float4*)B)[k] = p1[k]; }
#pragma unroll
        for (int c = 0; c < 40; ++c) xs[c][tid] = __floats2half2_rn(A[c], B[c]);
    }
    // no __syncthreads: each thread reads only its own column

    // ---- normalization constants (uniform scalar loads, once) ----
    const float dx = 24.0f / 200000.0f;
    const float silu_c = 1.0f / sqrtf((partials[0] + partials[1] + partials[2] + partials[3]) * dx);
    const float sig_c  = 1.0f / sqrtf((partials[4] + partials[5] + partials[6] + partials[7]) * dx);

    float acc0[24], acc1[24];
#pragma unroll
    for (int w = 0; w < 24; ++w) { acc0[w] = 0.f; acc1[w] = 0.f; }

    // ---- s (x) s quadratic features: 136 symmetrized pairs ----
    const float* wp = wssc;
#pragma unroll 1
    for (int u = 0; u < 16; ++u) {
        float2 su = __half22float2(xs[u][tid]);
#pragma unroll 2
        for (int t2 = u; t2 < 16; ++t2) {
            float2 sv = __half22float2(xs[t2][tid]);
            float pr0 = su.x * sv.x;
            float pr1 = su.y * sv.y;
#pragma unroll
            for (int w = 0; w < 24; ++w) {
                acc0[w] = fmaf(pr0, wp[w], acc0[w]);
                acc1[w] = fmaf(pr1, wp[w], acc1[w]);
            }
            wp += 24;
        }
    }

    // ---- <v_u, v_t> features: 36 symmetrized pairs ----
    wp = wvvc;
#pragma unroll 1
    for (int u = 0; u < 8; ++u) {
        float2 a0 = __half22float2(xs[16 + 3 * u + 0][tid]);
        float2 a1 = __half22float2(xs[16 + 3 * u + 1][tid]);
        float2 a2 = __half22float2(xs[16 + 3 * u + 2][tid]);
#pragma unroll 2
        for (int t2 = u; t2 < 8; ++t2) {
            float2 b0 = __half22float2(xs[16 + 3 * t2 + 0][tid]);
            float2 b1 = __half22float2(xs[16 + 3 * t2 + 1][tid]);
            float2 b2 = __half22float2(xs[16 + 3 * t2 + 2][tid]);
            float d0 = a0.x * b0.x; d0 = fmaf(a1.x, b1.x, d0); d0 = fmaf(a2.x, b2.x, d0);
            float d1 = a0.y * b0.y; d1 = fmaf(a1.y, b1.y, d1); d1 = fmaf(a2.y, b2.y, d1);
#pragma unroll
            for (int w = 0; w < 24; ++w) {
                acc0[w] = fmaf(d0, wp[w], acc0[w]);
                acc1[w] = fmaf(d1, wp[w], acc1[w]);
            }
            wp += 24;
        }
    }

    // ---- activations; store out_s early to retire acc registers ----
    float gate0[8], gate1[8];
    {
        float o0[16] __attribute__((aligned(16)));
        float o1[16] __attribute__((aligned(16)));
#pragma unroll
        for (int w = 0; w < 16; ++w) {
            float z0 = acc0[w], z1 = acc1[w];
            o0[w] = silu_c * z0 / (1.f + __expf(-z0));
            o1[w] = silu_c * z1 / (1.f + __expf(-z1));
        }
#pragma unroll
        for (int w = 0; w < 8; ++w) {
            gate0[w] = sig_c / (1.f + __expf(-acc0[16 + w]));
            gate1[w] = sig_c / (1.f + __expf(-acc1[16 + w]));
        }
        if (r0 < n) {
            float4* q = (float4*)(out + (size_t)r0 * 40);
#pragma unroll
            for (int k = 0; k < 4; ++k) q[k] = ((const float4*)o0)[k];
        }
        if (r1 < n) {
            float4* q = (float4*)(out + (size_t)r1 * 40);
#pragma unroll
            for (int k = 0; k < 4; ++k) q[k] = ((const float4*)o1)[k];
        }
    }

    // ---- gated[w][i] = sum_b v[b][i] * (sum_a s[a]*Wg[b][a][w]) ----
    float g0[24], g1[24];
#pragma unroll
    for (int k = 0; k < 24; ++k) { g0[k] = 0.f; g1[k] = 0.f; }
#pragma unroll 1
    for (int b = 0; b < 8; ++b) {
        float2 vb0 = __half22float2(xs[16 + 3 * b + 0][tid]);
        float2 vb1 = __half22float2(xs[16 + 3 * b + 1][tid]);
        float2 vb2 = __half22float2(xs[16 + 3 * b + 2][tid]);
        const float* wq = wgc + b * 128;
        float t0[8], t1[8];
#pragma unroll
        for (int w = 0; w < 8; ++w) { t0[w] = 0.f; t1[w] = 0.f; }
#pragma unroll 2
        for (int a = 0; a < 16; ++a) {
            float2 sa = __half22float2(xs[a][tid]);
            const float* wr = wq + a * 8;
#pragma unroll
            for (int w = 0; w < 8; ++w) {
                t0[w] = fmaf(sa.x, wr[w], t0[w]);
                t1[w] = fmaf(sa.y, wr[w], t1[w]);
            }
        }
#pragma unroll
        for (int w = 0; w < 8; ++w) {
            g0[3 * w + 0] = fmaf(t0[w], vb0.x, g0[3 * w + 0]);
            g0[3 * w + 1] = fmaf(t0[w], vb1.x, g0[3 * w + 1]);
            g0[3 * w + 2] = fmaf(t0[w], vb2.x, g0[3 * w + 2]);
            g1[3 * w + 0] = fmaf(t1[w], vb0.y, g1[3 * w + 0]);
            g1[3 * w + 1] = fmaf(t1[w], vb1.y, g1[3 * w + 1]);
            g1[3 * w + 2] = fmaf(t1[w], vb2.y, g1[3 * w + 2]);
        }
    }

    // ---- gate and store out_v ----
    {
        float o0[24] __attribute__((aligned(16)));
        float o1[24] __attribute__((aligned(16)));
#pragma unroll
        for (int w = 0; w < 8; ++w) {
#pragma unroll
            for (int i = 0; i < 3; ++i) {
                o0[3 * w + i] = gate0[w] * g0[3 * w + i];
                o1[3 * w + i] = gate1[w] * g1[3 * w + i];
            }
        }
        if (r0 < n) {
            float4* q = (float4*)(out + (size_t)r0 * 40 + 16);
#pragma unroll
            for (int k = 0; k < 6; ++k) q[k] = ((const float4*)o0)[k];
        }
        if (r1 < n) {
            float4* q = (float4*)(out + (size_t)r1 * 40 + 16);
#pragma unroll
            for (int k = 0; k < 6; ++k) q[k] = ((const float4*)o1)[k];
        }
    }
}

// ---------------------------------------------------------------------------
extern "C" void kernel_launch(void* const* d_in, const int* in_sizes, int n_in,
                              void* d_out, int out_size, void* d_ws, size_t ws_size,
                              hipStream_t stream)
{
    (void)n_in; (void)out_size; (void)ws_size;
    const float* x    = (const float*)d_in[0];
    const float* wss0 = (const float*)d_in[1];
    const float* wvv0 = (const float*)d_in[2];
    const float* wss1 = (const float*)d_in[3];
    const float* wvv1 = (const float*)d_in[4];
    const float* wsv  = (const float*)d_in[5];
    const float* wvs  = (const float*)d_in[6];
    float* out = (float*)d_out;
    const int n = in_sizes[0] / 40;

    char* ws = (char*)d_ws;
    float* partials = (float*)(ws + 0);        // 8 floats
    float* wssc     = (float*)(ws + 4096);     // 3264 floats
    float* wvvc     = (float*)(ws + 17408);    // 864 floats
    float* wgc      = (float*)(ws + 21504);    // 1024 floats

    hipLaunchKernelGGL(prep, dim3(25), dim3(256), 0, stream,
                       wss0, wvv0, wss1, wvv1, wsv, wvs, partials, wssc, wvvc, wgc);
    hipLaunchKernelGGL(seg_main, dim3((n + 511) / 512), dim3(256), 0, stream,
                       x, wssc, wvvc, wgc, partials, out, n);
}